// Round 1
// baseline (373.746 us; speedup 1.0000x reference)
//
#include <hip/hip_runtime.h>
#include <cstdint>
#include <cstddef>

#define IN_F 4096
#define OUT_F 4096
#define NROWS 8192
#define BM 128
#define BN 128
#define BK 32

typedef float f32x4 __attribute__((ext_vector_type(4)));
typedef short s16x8 __attribute__((ext_vector_type(8)));

// round-to-nearest-even fp32 -> bf16 (inputs finite)
__device__ inline unsigned short f2bf_rne(float f) {
    unsigned int u = __float_as_uint(f);
    u += 0x7FFFu + ((u >> 16) & 1u);
    return (unsigned short)(u >> 16);
}

// w[o][t] = 2*norm(o)*sin(pi*(o+1)*(2t+1)/8192), norm = rsqrt(2*IN*(o==0?2:1))
// integer-exact reduction: sin(pi*n/8192) has period n mod 16384
__global__ void build_w(const float* __restrict__ fc, unsigned short* __restrict__ wb) {
    int gid = blockIdx.x * 256 + threadIdx.x;   // OUT_F*IN_F/8 threads
    int o = gid >> 9;                           // IN_F/8 = 512 groups per row
    int t0 = (gid & 511) << 3;
    int k = (int)fc[o];                         // fc = arange(OUT) at init
    float amp = 2.0f * rsqrtf(2.0f * (float)IN_F * ((k == 0) ? 2.0f : 1.0f));
    unsigned int op1 = (unsigned int)(k + 1);
    union { s16x8 v; unsigned short s[8]; } p;
#pragma unroll
    for (int j = 0; j < 8; ++j) {
        unsigned int t = (unsigned int)(t0 + j);
        unsigned int r = (op1 * (2u * t + 1u)) & 16383u;
        float ang = (float)r * 3.83495196971410293e-4f;  // pi/8192
        p.s[j] = f2bf_rne(amp * __sinf(ang));
    }
    *reinterpret_cast<s16x8*>(&wb[(size_t)gid * 8]) = p.v;
}

__global__ void convert_x(const float* __restrict__ x, unsigned short* __restrict__ xb) {
    size_t gid = (size_t)blockIdx.x * 256 + threadIdx.x;  // NROWS*IN_F/8 threads
    const f32x4* xv = reinterpret_cast<const f32x4*>(x) + gid * 2;
    f32x4 a = xv[0], b = xv[1];
    union { s16x8 v; unsigned short s[8]; } p;
    p.s[0] = f2bf_rne(a[0]); p.s[1] = f2bf_rne(a[1]);
    p.s[2] = f2bf_rne(a[2]); p.s[3] = f2bf_rne(a[3]);
    p.s[4] = f2bf_rne(b[0]); p.s[5] = f2bf_rne(b[1]);
    p.s[6] = f2bf_rne(b[2]); p.s[7] = f2bf_rne(b[3]);
    *reinterpret_cast<s16x8*>(&xb[gid * 8]) = p.v;
}

template <bool ABF16>
__global__ __launch_bounds__(256) void gemm_dst(
        const float* __restrict__ xf, const unsigned short* __restrict__ xb,
        const unsigned short* __restrict__ wb, const float* __restrict__ bias,
        float* __restrict__ out) {
    __shared__ unsigned short As[BM * BK];  // 8 KB
    __shared__ unsigned short Bs[BN * BK];  // 8 KB

    const int tid = threadIdx.x;
    const int bid = blockIdx.x;
    // XCD-aware swizzle: 2048 wgs, 8 XCDs, 256 per XCD (bijective)
    const int swz = (bid & 7) * 256 + (bid >> 3);
    const int brow = (swz >> 5) * BM;   // 64 row panels
    const int bcol = (swz & 31) * BN;   // 32 col panels
    const int lane = tid & 63;
    const int wave = tid >> 6;
    const int wr = (wave >> 1) * 64;    // wave row offset in tile
    const int wc = (wave & 1) * 64;     // wave col offset in tile
    const int lr = lane & 15;
    const int kq = lane >> 4;

    f32x4 acc[4][4];
#pragma unroll
    for (int m = 0; m < 4; ++m)
#pragma unroll
        for (int n = 0; n < 4; ++n)
            acc[m][n] = (f32x4){0.f, 0.f, 0.f, 0.f};

    const int bli = tid * 8;       // linear element index for global_load_lds
    const int br0 = bli >> 5;      // tile row (32 elems per row)
    const int bk0 = bli & 31;

    for (int kt = 0; kt < IN_F; kt += BK) {
        // ---- stage B (W bf16) via global_load_lds, 2 x 16B per thread ----
        __builtin_amdgcn_global_load_lds(
            (const __attribute__((address_space(1))) unsigned int*)(wb + (size_t)(bcol + br0) * IN_F + kt + bk0),
            (__attribute__((address_space(3))) unsigned int*)(&Bs[bli]), 16, 0, 0);
        __builtin_amdgcn_global_load_lds(
            (const __attribute__((address_space(1))) unsigned int*)(wb + (size_t)(bcol + br0 + 64) * IN_F + kt + bk0),
            (__attribute__((address_space(3))) unsigned int*)(&Bs[bli + 2048]), 16, 0, 0);
        // ---- stage A ----
        if (ABF16) {
            __builtin_amdgcn_global_load_lds(
                (const __attribute__((address_space(1))) unsigned int*)(xb + (size_t)(brow + br0) * IN_F + kt + bk0),
                (__attribute__((address_space(3))) unsigned int*)(&As[bli]), 16, 0, 0);
            __builtin_amdgcn_global_load_lds(
                (const __attribute__((address_space(1))) unsigned int*)(xb + (size_t)(brow + br0 + 64) * IN_F + kt + bk0),
                (__attribute__((address_space(3))) unsigned int*)(&As[bli + 2048]), 16, 0, 0);
        } else {
            // reg-stage: load 16 fp32, convert, 2 x ds_write_b128
            const int ar = tid >> 1;
            const int ak = (tid & 1) * 16;
            const f32x4* src = reinterpret_cast<const f32x4*>(xf + (size_t)(brow + ar) * IN_F + kt + ak);
            f32x4 f0 = src[0], f1 = src[1], f2 = src[2], f3 = src[3];
            union { s16x8 v; unsigned short s[8]; } p0, p1;
            p0.s[0] = f2bf_rne(f0[0]); p0.s[1] = f2bf_rne(f0[1]);
            p0.s[2] = f2bf_rne(f0[2]); p0.s[3] = f2bf_rne(f0[3]);
            p0.s[4] = f2bf_rne(f1[0]); p0.s[5] = f2bf_rne(f1[1]);
            p0.s[6] = f2bf_rne(f1[2]); p0.s[7] = f2bf_rne(f1[3]);
            p1.s[0] = f2bf_rne(f2[0]); p1.s[1] = f2bf_rne(f2[1]);
            p1.s[2] = f2bf_rne(f2[2]); p1.s[3] = f2bf_rne(f2[3]);
            p1.s[4] = f2bf_rne(f3[0]); p1.s[5] = f2bf_rne(f3[1]);
            p1.s[6] = f2bf_rne(f3[2]); p1.s[7] = f2bf_rne(f3[3]);
            *reinterpret_cast<s16x8*>(&As[ar * BK + ak]) = p0.v;
            *reinterpret_cast<s16x8*>(&As[ar * BK + ak + 8]) = p1.v;
        }
        __syncthreads();
        // ---- compute ----
        s16x8 af[4], bfr[4];
#pragma unroll
        for (int m = 0; m < 4; ++m)
            af[m] = *reinterpret_cast<const s16x8*>(&As[(wr + m * 16 + lr) * BK + kq * 8]);
#pragma unroll
        for (int n = 0; n < 4; ++n)
            bfr[n] = *reinterpret_cast<const s16x8*>(&Bs[(wc + n * 16 + lr) * BK + kq * 8]);
#pragma unroll
        for (int m = 0; m < 4; ++m)
#pragma unroll
            for (int n = 0; n < 4; ++n)
                acc[m][n] = __builtin_amdgcn_mfma_f32_16x16x32_bf16(af[m], bfr[n], acc[m][n], 0, 0, 0);
        __syncthreads();
    }

    // ---- epilogue: C[row][col] = acc + bias; D layout: col=lane&15, row=(lane>>4)*4+j ----
    float bv[4];
#pragma unroll
    for (int n = 0; n < 4; ++n) bv[n] = bias[bcol + wc + n * 16 + lr];
#pragma unroll
    for (int m = 0; m < 4; ++m) {
#pragma unroll
        for (int j = 0; j < 4; ++j) {
            const int row = brow + wr + m * 16 + kq * 4 + j;
            float* orow = out + (size_t)row * OUT_F + bcol + wc + lr;
#pragma unroll
            for (int n = 0; n < 4; ++n)
                orow[n * 16] = acc[m][n][j] + bv[n];
        }
    }
}

// last-resort fallback if workspace is too small for W (compute w on the fly)
__global__ void fallback_kernel(const float* __restrict__ x, const float* __restrict__ fc,
                                const float* __restrict__ bias, float* __restrict__ out) {
    __shared__ float xrow[IN_F];  // 16 KB
    const int o = blockIdx.x * 256 + threadIdx.x;
    const int n = blockIdx.y;
    for (int i = threadIdx.x; i < IN_F; i += 256)
        xrow[i] = x[(size_t)n * IN_F + i];
    __syncthreads();
    const int k = (int)fc[o];
    const float amp = 2.0f * rsqrtf(2.0f * (float)IN_F * ((k == 0) ? 2.0f : 1.0f));
    const unsigned int op1 = (unsigned int)(k + 1);
    float s = 0.f;
    for (int t = 0; t < IN_F; ++t) {
        unsigned int r = (op1 * (2u * (unsigned int)t + 1u)) & 16383u;
        s += xrow[t] * __sinf((float)r * 3.83495196971410293e-4f);
    }
    out[(size_t)n * OUT_F + o] = amp * s + bias[o];
}

extern "C" void kernel_launch(void* const* d_in, const int* in_sizes, int n_in,
                              void* d_out, int out_size, void* d_ws, size_t ws_size,
                              hipStream_t stream) {
    const float* x    = (const float*)d_in[0];
    const float* fc   = (const float*)d_in[1];
    const float* bias = (const float*)d_in[2];
    float* out = (float*)d_out;

    const size_t WBYTES = (size_t)OUT_F * IN_F * 2;   // 32 MB
    const size_t XBYTES = (size_t)NROWS * IN_F * 2;   // 64 MB

    if (ws_size >= WBYTES) {
        unsigned short* wb = (unsigned short*)d_ws;
        build_w<<<OUT_F * IN_F / 8 / 256, 256, 0, stream>>>(fc, wb);
        const int grid = (NROWS / BM) * (OUT_F / BN);  // 2048
        if (ws_size >= WBYTES + XBYTES) {
            unsigned short* xb = (unsigned short*)((char*)d_ws + WBYTES);
            convert_x<<<NROWS * IN_F / 8 / 256, 256, 0, stream>>>(x, xb);
            gemm_dst<true><<<grid, 256, 0, stream>>>(x, xb, wb, bias, out);
        } else {
            gemm_dst<false><<<grid, 256, 0, stream>>>(x, (const unsigned short*)nullptr, wb, bias, out);
        }
    } else {
        dim3 g(OUT_F / 256, NROWS);
        fallback_kernel<<<g, 256, 0, stream>>>(x, fc, bias, out);
    }
}

// Round 2
// 279.410 us; speedup vs baseline: 1.3376x; 1.3376x over previous
//
#include <hip/hip_runtime.h>
#include <cstdint>
#include <cstddef>

#define IN_F 4096
#define OUT_F 4096
#define NROWS 8192
#define BM 256
#define BN 256
#define BK 32
#define NT (IN_F / BK)   // 128 K-tiles

typedef float f32x4 __attribute__((ext_vector_type(4)));
typedef short s16x8 __attribute__((ext_vector_type(8)));

// round-to-nearest-even fp32 -> bf16
__device__ inline unsigned short f2bf_rne(float f) {
    unsigned int u = __float_as_uint(f);
    u += 0x7FFFu + ((u >> 16) & 1u);
    return (unsigned short)(u >> 16);
}

// w[o][t] = 2*norm(o)*sin(pi*(o+1)*(2t+1)/8192); integer-exact arg reduction mod 16384
__global__ void build_w(const float* __restrict__ fc, unsigned short* __restrict__ wb) {
    int gid = blockIdx.x * 256 + threadIdx.x;
    int o = gid >> 9;
    int t0 = (gid & 511) << 3;
    int k = (int)fc[o];
    float amp = 2.0f * rsqrtf(2.0f * (float)IN_F * ((k == 0) ? 2.0f : 1.0f));
    unsigned int op1 = (unsigned int)(k + 1);
    union { s16x8 v; unsigned short s[8]; } p;
#pragma unroll
    for (int j = 0; j < 8; ++j) {
        unsigned int t = (unsigned int)(t0 + j);
        unsigned int r = (op1 * (2u * t + 1u)) & 16383u;
        float ang = (float)r * 3.83495196971410293e-4f;  // pi/8192
        p.s[j] = f2bf_rne(amp * __sinf(ang));
    }
    *reinterpret_cast<s16x8*>(&wb[(size_t)gid * 8]) = p.v;
}

__global__ void convert_x(const float* __restrict__ x, unsigned short* __restrict__ xb) {
    size_t gid = (size_t)blockIdx.x * 256 + threadIdx.x;
    const f32x4* xv = reinterpret_cast<const f32x4*>(x) + gid * 2;
    f32x4 a = xv[0], b = xv[1];
    union { s16x8 v; unsigned short s[8]; } p;
    p.s[0] = f2bf_rne(a[0]); p.s[1] = f2bf_rne(a[1]);
    p.s[2] = f2bf_rne(a[2]); p.s[3] = f2bf_rne(a[3]);
    p.s[4] = f2bf_rne(b[0]); p.s[5] = f2bf_rne(b[1]);
    p.s[6] = f2bf_rne(b[2]); p.s[7] = f2bf_rne(b[3]);
    *reinterpret_cast<s16x8*>(&xb[gid * 8]) = p.v;
}

__device__ inline void wg_barrier() {
    asm volatile("" ::: "memory");
    __builtin_amdgcn_s_barrier();
    asm volatile("" ::: "memory");
}

#define GLD(gsrc, ldst) __builtin_amdgcn_global_load_lds( \
    (const __attribute__((address_space(1))) unsigned int*)(gsrc), \
    (__attribute__((address_space(3))) unsigned int*)(ldst), 16, 0, 0)

#define STAGE_A(T) do { \
    const int _sb = ((T) & 3) * 32768; \
    const int _sk = (T) * BK; \
    GLD(gA + _sk, (char*)lds + _sb + ldsA0); \
    GLD(gA2 + _sk, (char*)lds + _sb + ldsA1); \
} while (0)

#define STAGE_B(T) do { \
    const int _sb = ((T) & 3) * 32768; \
    const int _sk = (T) * BK; \
    GLD(gB + _sk, (char*)lds + _sb + ldsB0); \
    GLD(gB2 + _sk, (char*)lds + _sb + ldsB1); \
} while (0)

#define MFMA1(d, a, b) d = __builtin_amdgcn_mfma_f32_16x16x32_bf16(a, b, d, 0, 0, 0)
#define MF4(M, A) do { MFMA1(acc[M][0], A, b0); MFMA1(acc[M][1], A, b1); \
                       MFMA1(acc[M][2], A, b2); MFMA1(acc[M][3], A, b3); } while (0)

#define LD_AS(name, off) s16x8 name = *(const s16x8*)((const char*)lds + (off))

// One K-tile (BK=32): 2 phases x {ds_read || stage || barrier || lgkm || 16 MFMA}.
// Counted vmcnt(VM) once per tile, never 0 in steady state.
#define TILE(T, DO_STAGE, VM) do { \
    const int _bb = ((T) & 3) * 32768; \
    LD_AS(a0, _bb + aoff + 0); \
    LD_AS(a1, _bb + aoff + 1024); \
    LD_AS(a2, _bb + aoff + 2048); \
    LD_AS(a3, _bb + aoff + 3072); \
    LD_AS(b0, _bb + boff + 0); \
    LD_AS(b1, _bb + boff + 1024); \
    LD_AS(b2, _bb + boff + 2048); \
    LD_AS(b3, _bb + boff + 3072); \
    if (DO_STAGE) STAGE_A((T) + 3); \
    wg_barrier(); \
    asm volatile("s_waitcnt lgkmcnt(0)" ::: "memory"); \
    __builtin_amdgcn_sched_barrier(0); \
    __builtin_amdgcn_s_setprio(1); \
    MF4(0, a0); MF4(1, a1); MF4(2, a2); MF4(3, a3); \
    __builtin_amdgcn_s_setprio(0); \
    wg_barrier(); \
    LD_AS(a4, _bb + aoff + 4096); \
    LD_AS(a5, _bb + aoff + 5120); \
    LD_AS(a6, _bb + aoff + 6144); \
    LD_AS(a7, _bb + aoff + 7168); \
    if (DO_STAGE) STAGE_B((T) + 3); \
    wg_barrier(); \
    asm volatile("s_waitcnt lgkmcnt(0)" ::: "memory"); \
    __builtin_amdgcn_sched_barrier(0); \
    __builtin_amdgcn_s_setprio(1); \
    MF4(4, a4); MF4(5, a5); MF4(6, a6); MF4(7, a7); \
    __builtin_amdgcn_s_setprio(0); \
    asm volatile("s_waitcnt vmcnt(" #VM ")" ::: "memory"); \
    wg_barrier(); \
} while (0)

__global__ __launch_bounds__(512, 2) void gemm_dst(
        const unsigned short* __restrict__ xb, const unsigned short* __restrict__ wb,
        const float* __restrict__ bias, float* __restrict__ out) {
    // 4-deep circular buffer: [buf][A 16KB | B 16KB] = 128 KB
    __shared__ unsigned short lds[65536];

    const int tid = threadIdx.x;
    const int lane = tid & 63;
    const int wave = tid >> 6;
    const int wave_m = wave >> 2;   // 0..1 -> 128-row half
    const int wave_n = wave & 3;    // 0..3 -> 64-col quarter
    const int lr = lane & 15;
    const int kq = lane >> 4;

    const int bid = blockIdx.x;
    // XCD swizzle: 512 wgs, 64 per XCD; within XCD, 16 consecutive share the A row-panel
    const int swz = (bid & 7) * 64 + (bid >> 3);
    const int brow = (swz >> 4) * BM;   // 32 row panels
    const int bcol = (swz & 15) * BN;   // 16 col panels

    // ---- stage addressing: slot p = tid + j*512; row=p>>2; kq_l=(p&3)^((row>>1)&3) ----
    const int srow = tid >> 2;                    // +128 for j=1
    const int skq = (tid & 3) ^ ((tid >> 3) & 3); // constant per thread
    const unsigned short* gA  = xb + (size_t)(brow + srow) * IN_F + skq * 8;
    const unsigned short* gA2 = gA + (size_t)128 * IN_F;
    const unsigned short* gB  = wb + (size_t)(bcol + srow) * IN_F + skq * 8;
    const unsigned short* gB2 = gB + (size_t)128 * IN_F;
    const int ldsA0 = tid * 16;
    const int ldsA1 = tid * 16 + 8192;
    const int ldsB0 = tid * 16 + 16384;
    const int ldsB1 = tid * 16 + 24576;

    // ---- ds_read addressing: swizzled col byte = (kq ^ ((lr>>1)&3))<<4 ----
    const int colsw = ((kq ^ ((lr >> 1) & 3)) << 4);
    const int aoff = (wave_m * 128 + lr) * 64 + colsw;           // + m*1024
    const int boff = 16384 + (wave_n * 64 + lr) * 64 + colsw;    // + n*1024

    f32x4 acc[8][4];
#pragma unroll
    for (int m = 0; m < 8; ++m)
#pragma unroll
        for (int n = 0; n < 4; ++n)
            acc[m][n] = (f32x4){0.f, 0.f, 0.f, 0.f};

    // ---- prologue: stage tiles 0,1,2 (12 loads/wave); retire tile 0 ----
    STAGE_A(0); STAGE_B(0);
    STAGE_A(1); STAGE_B(1);
    STAGE_A(2); STAGE_B(2);
    asm volatile("s_waitcnt vmcnt(8)" ::: "memory");
    wg_barrier();

    // ---- main loop: compute buf[t&3], stage tile t+3 into buf[(t+3)&3] ----
#pragma unroll 4
    for (int t = 0; t < NT - 3; ++t) {
        TILE(t, 1, 8);
    }
    // ---- tail: drain 8 -> 4 -> 0 ----
    TILE(NT - 3, 0, 4);
    TILE(NT - 2, 0, 0);
    TILE(NT - 1, 0, 0);

    // ---- epilogue: C = acc + bias; D layout col=lane&15, row=(lane>>4)*4+j ----
    const int ccol0 = bcol + wave_n * 64 + lr;
    const int crow0 = brow + wave_m * 128 + kq * 4;
    float bv[4];
#pragma unroll
    for (int n = 0; n < 4; ++n) bv[n] = bias[ccol0 + n * 16];
#pragma unroll
    for (int m = 0; m < 8; ++m) {
#pragma unroll
        for (int j = 0; j < 4; ++j) {
            float* orow = out + (size_t)(crow0 + m * 16 + j) * OUT_F + ccol0;
#pragma unroll
            for (int n = 0; n < 4; ++n)
                orow[n * 16] = acc[m][n][j] + bv[n];
        }
    }
}

// last-resort fallback if workspace is too small (naive on-the-fly DST)
__global__ void fallback_kernel(const float* __restrict__ x, const float* __restrict__ fc,
                                const float* __restrict__ bias, float* __restrict__ out) {
    __shared__ float xrow[IN_F];
    const int o = blockIdx.x * 256 + threadIdx.x;
    const int n = blockIdx.y;
    for (int i = threadIdx.x; i < IN_F; i += 256)
        xrow[i] = x[(size_t)n * IN_F + i];
    __syncthreads();
    const int k = (int)fc[o];
    const float amp = 2.0f * rsqrtf(2.0f * (float)IN_F * ((k == 0) ? 2.0f : 1.0f));
    const unsigned int op1 = (unsigned int)(k + 1);
    float s = 0.f;
    for (int t = 0; t < IN_F; ++t) {
        unsigned int r = (op1 * (2u * (unsigned int)t + 1u)) & 16383u;
        s += xrow[t] * __sinf((float)r * 3.83495196971410293e-4f);
    }
    out[(size_t)n * OUT_F + o] = amp * s + bias[o];
}

extern "C" void kernel_launch(void* const* d_in, const int* in_sizes, int n_in,
                              void* d_out, int out_size, void* d_ws, size_t ws_size,
                              hipStream_t stream) {
    const float* x    = (const float*)d_in[0];
    const float* fc   = (const float*)d_in[1];
    const float* bias = (const float*)d_in[2];
    float* out = (float*)d_out;

    const size_t WBYTES = (size_t)OUT_F * IN_F * 2;   // 32 MB
    const size_t XBYTES = (size_t)NROWS * IN_F * 2;   // 64 MB

    if (ws_size >= WBYTES + XBYTES) {
        unsigned short* wb = (unsigned short*)d_ws;
        unsigned short* xb = (unsigned short*)((char*)d_ws + WBYTES);
        build_w<<<OUT_F * IN_F / 8 / 256, 256, 0, stream>>>(fc, wb);
        convert_x<<<NROWS * IN_F / 8 / 256, 256, 0, stream>>>(x, xb);
        const int grid = (NROWS / BM) * (OUT_F / BN);  // 512
        gemm_dst<<<grid, 512, 0, stream>>>(xb, wb, bias, out);
    } else {
        dim3 g(OUT_F / 256, NROWS);
        fallback_kernel<<<g, 256, 0, stream>>>(x, fc, bias, out);
    }
}